// Round 7
// baseline (66.489 us; speedup 1.0000x reference)
//
#include <hip/hip_runtime.h>

#define B_ 2
#define A_ 16384
#define C_ 15
#define G_ 16
#define D2Rf 0.017453292519943295f
#define ENC_HALF 0xBF000000u   // enc(0.5f)
#define ENC_04   0xBECCCCCDu   // enc(0.4f)
#define MB_ 128                // mega blocks (co-resident on 256 CUs)
#define MT_ 256                // threads per block; MB_*MT_ == B_*A_
#define PKSTRIDE 16            // u64 stride between padded colmax cells (128 B)

__device__ __forceinline__ unsigned enc_f32(float f) {
    unsigned u = __float_as_uint(f);
    return u ^ ((u >> 31) ? 0xFFFFFFFFu : 0x80000000u);
}

// ---------------------------------------------------------------------------
// Rotated IoU, replicating the JAX reference op-for-op in fp32.
// (verified absmax 0.0 in R1-R6; all indexing compile-time static)
// ---------------------------------------------------------------------------
__device__ __forceinline__ void rect_corners5(const float* b, float X[4], float Y[4],
                                              float* cth, float* sth) {
    float th = b[4] * D2Rf;
    float c = cosf(th), s = sinf(th);
    *cth = c; *sth = s;
    const float SX[4] = {-1.f, 1.f, 1.f, -1.f};
    const float SY[4] = {-1.f, -1.f, 1.f, 1.f};
    float hw = 0.5f * b[2], hh = 0.5f * b[3];
#pragma unroll
    for (int i = 0; i < 4; ++i) {
        float dx = hw * SX[i];
        float dy = hh * SY[i];
        X[i] = b[0] + dx * c - dy * s;
        Y[i] = b[1] + dx * s + dy * c;
    }
}

__device__ __forceinline__ float rotated_iou_pair(const float* ab, const float* gb) {
    float ax[4], ay[4], gx[4], gy[4];
    float cA, sA, cG, sG;
    rect_corners5(ab, ax, ay, &cA, &sA);
    rect_corners5(gb, gx, gy, &cG, &sG);

    float rx[24], ry[24];
    unsigned msk = 0u;

#pragma unroll
    for (int i = 0; i < 4; ++i) {
        float dx = ax[i] - gb[0], dy = ay[i] - gb[1];
        float lx = dx * cG + dy * sG;
        float ly = -dx * sG + dy * cG;
        bool in = (fabsf(lx) <= 0.5f * gb[2] + 1e-4f) && (fabsf(ly) <= 0.5f * gb[3] + 1e-4f);
        rx[i] = ax[i]; ry[i] = ay[i];
        if (in) msk |= (1u << i);
    }
#pragma unroll
    for (int i = 0; i < 4; ++i) {
        float dx = gx[i] - ab[0], dy = gy[i] - ab[1];
        float lx = dx * cA + dy * sA;
        float ly = -dx * sA + dy * cA;
        bool in = (fabsf(lx) <= 0.5f * ab[2] + 1e-4f) && (fabsf(ly) <= 0.5f * ab[3] + 1e-4f);
        rx[4 + i] = gx[i]; ry[4 + i] = gy[i];
        if (in) msk |= (1u << (4 + i));
    }
#pragma unroll
    for (int i = 0; i < 4; ++i) {
        float p0x = ax[i], p0y = ay[i];
        float p1x = ax[(i + 1) & 3], p1y = ay[(i + 1) & 3];
        float d1x = p1x - p0x, d1y = p1y - p0y;
#pragma unroll
        for (int j = 0; j < 4; ++j) {
            float q0x = gx[j], q0y = gy[j];
            float q1x = gx[(j + 1) & 3], q1y = gy[(j + 1) & 3];
            float d2x = q1x - q0x, d2y = q1y - q0y;
            float rrx = q0x - p0x, rry = q0y - p0y;
            float den = d1x * d2y - d1y * d2x;
            float safe = (fabsf(den) < 1e-8f) ? 1.f : den;
            float t = (rrx * d2y - rry * d2x) / safe;
            float u = (rrx * d1y - rry * d1x) / safe;
            bool ok = (fabsf(den) >= 1e-8f) && (t >= 0.f) && (t <= 1.f) && (u >= 0.f) && (u <= 1.f);
            int k = 8 + i * 4 + j;
            rx[k] = p0x + t * d1x;
            ry[k] = p0y + t * d1y;
            if (ok) msk |= (1u << k);
        }
    }

    int cnt = __popc(msk);
    float sx = 0.f, sy = 0.f;
#pragma unroll
    for (int k = 0; k < 24; ++k)
        if ((msk >> k) & 1u) { sx += rx[k]; sy += ry[k]; }
    float cnf = fmaxf((float)cnt, 1.f);
    float cenx = sx / cnf, ceny = sy / cnf;

    float ang[24];
#pragma unroll
    for (int k = 0; k < 24; ++k) {
        if ((msk >> k) & 1u) {
            rx[k] -= cenx; ry[k] -= ceny;
            ang[k] = atan2f(ry[k], rx[k]);
        } else {
            rx[k] = 0.f; ry[k] = 0.f;
            ang[k] = 1e9f;
        }
    }

    int rnk[24];
#pragma unroll
    for (int k = 0; k < 24; ++k) {
        int r = 0;
#pragma unroll
        for (int j = 0; j < 24; ++j)
            r += (ang[j] < ang[k]) || (ang[j] == ang[k] && j < k);
        rnk[k] = r;
    }

    float ssum = 0.f;
#pragma unroll
    for (int k = 0; k < 24; ++k) {
        if ((msk >> k) & 1u) {
            int tgt = (rnk[k] + 1 == cnt) ? 0 : rnk[k] + 1;
            float qx = 0.f, qy = 0.f;
#pragma unroll
            for (int j = 0; j < 24; ++j) {
                if (((msk >> j) & 1u) && rnk[j] == tgt) { qx = rx[j]; qy = ry[j]; }
            }
            ssum += rx[k] * qy - ry[k] * qx;
        }
    }
    float inter = (cnt >= 3) ? 0.5f * fabsf(ssum) : 0.f;
    float uni = ab[2] * ab[3] + gb[2] * gb[3] - inter;
    return inter / fmaxf(uni, 1e-8f);
}

// ---------------------------------------------------------------------------
// init: zero counters + padded colmax cells (one cheap kernel node; a 4-byte
// hipMemsetAsync fill node measured ~39us in R3 -- pathological, avoid).
// ws u32 layout: [0]=gctr [1]=bar1 [2]=bar2 [3]=done ; u64 pk at +256B.
// ---------------------------------------------------------------------------
__global__ void init_kernel(unsigned* __restrict__ ctr,
                            unsigned long long* __restrict__ pk) {
    if (threadIdx.x < 4) ctr[threadIdx.x] = 0u;
    for (int i = threadIdx.x; i < 32 * PKSTRIDE; i += 256) pk[i] = 0ull;
}

// ---------------------------------------------------------------------------
// mega: gate -> barrier -> balanced heavy -> barrier -> colfinal+loss+final.
// 128 blocks x 256 threads (= one thread per anchor for gate/loss phases).
// All cross-block combines are max over monotone packed keys or fixed-order
// sums -> deterministic although worklist order varies per replay.
// ---------------------------------------------------------------------------
__global__ void __launch_bounds__(MT_, 1)
mega_kernel(const float* __restrict__ cls_p,
            const float* __restrict__ reg_p,
            const float* __restrict__ anc,
            const float* __restrict__ ann,
            unsigned* __restrict__ ctr,
            unsigned long long* __restrict__ pk,     // padded 32*PKSTRIDE
            unsigned* __restrict__ wl,               // up to B_*A_*G_ entries
            unsigned long long* __restrict__ rowMaxArg,  // B_*A_
            float* __restrict__ pcls,
            float* __restrict__ preg,
            int* __restrict__ pnp,
            float* __restrict__ out) {
    __shared__ int ss[MT_];
    __shared__ unsigned sbase;
    __shared__ unsigned long long cells[32];
    __shared__ unsigned long long pk32[32];
    __shared__ float sc[MT_], sr[MT_];
    __shared__ int sp[MT_];
    __shared__ int lastFlag;

    const int tid = threadIdx.x;
    const int t = blockIdx.x * MT_ + tid;    // global anchor id
    const int b = t >> 14;

    if (tid < 32) cells[tid] = 0ull;

    // ================= phase 1: gate =================
    const float* ab = anc + (size_t)t * 5;
    float a0 = ab[0], a1 = ab[1], a2 = ab[2], a3 = ab[3];
    float sa = 0.5f * fmaxf(a2, a3);

    unsigned passmask = 0u;
    unsigned long long rk = 0ull;
#pragma unroll
    for (int g = 0; g < G_; ++g) {
        const float* gb = ann + ((size_t)b * G_ + g) * 6;  // uniform, cached
        float v;
        if (gb[5] == -1.0f) {
            v = -1.0f;
        } else {
            float sb = 0.5f * fmaxf(gb[2], gb[3]);
            float iw = fminf(a0 + sa, gb[0] + sb) - fmaxf(a0 - sa, gb[0] - sb);
            iw = fmaxf(iw, 0.f);
            float ih = fminf(a1 + sa, gb[1] + sb) - fmaxf(a1 - sa, gb[1] - sb);
            ih = fmaxf(ih, 0.f);
            float inter = iw * ih;
            float uni = 4.f * sa * sa + 4.f * sb * sb - inter;
            float ind = inter / fmaxf(uni, 1e-8f);
            if (ind > 0.1f) passmask |= (1u << g);
            v = 0.f;  // placeholder <= any heavy IoU, same tiebreak bits
        }
        unsigned long long key =
            ((unsigned long long)enc_f32(v) << 32) | (unsigned)(G_ - 1 - g);
        if (key > rk) rk = key;
    }
    rowMaxArg[t] = rk;

    // block scan -> one global atomicAdd -> compacted worklist append
    int cnt = __popc(passmask);
    ss[tid] = cnt;
    __syncthreads();
    for (int s = 1; s < MT_; s <<= 1) {
        int v = (tid >= s) ? ss[tid - s] : 0;
        __syncthreads();
        ss[tid] += v;
        __syncthreads();
    }
    if (tid == MT_ - 1) sbase = atomicAdd(&ctr[0], (unsigned)ss[MT_ - 1]);
    __syncthreads();
    unsigned p = sbase + (unsigned)(ss[tid] - cnt);
#pragma unroll
    for (int g = 0; g < G_; ++g) {
        if ((passmask >> g) & 1u) wl[p++] = ((unsigned)t << 4) | (unsigned)g;
    }

    // ================= grid barrier 1 =================
    __syncthreads();
    if (tid == 0) {
        __threadfence();
        atomicAdd(&ctr[1], 1u);
        while (atomicAdd(&ctr[1], 0u) < (unsigned)MB_) __builtin_amdgcn_s_sleep(1);
        __threadfence();
    }
    __syncthreads();

    // ================= phase 2: balanced heavy =================
    const unsigned n = atomicAdd(&ctr[0], 0u);
    for (unsigned i = (unsigned)(blockIdx.x * MT_ + tid); i < n; i += MB_ * MT_) {
        unsigned e = wl[i];
        int t2 = (int)(e >> 4), g = (int)(e & 15u);
        int b2 = t2 >> 14;
        const float* ab2 = anc + (size_t)t2 * 5;
        const float* gb2 = ann + ((size_t)b2 * G_ + g) * 6;
        float v = rotated_iou_pair(ab2, gb2);
        unsigned long long ev = (unsigned long long)enc_f32(v);
        atomicMax(&rowMaxArg[t2], (ev << 32) | (unsigned)(G_ - 1 - g));
        int aIdx = t2 & (A_ - 1);
        atomicMax(&cells[b2 * G_ + g], (ev << 32) | (0xFFFFFFFFu - (unsigned)aIdx));
    }
    __syncthreads();
    // fold block cells into padded global table: 4096 atomics over 32 lines
    if (tid < 32 && cells[tid] != 0ull) atomicMax(&pk[tid * PKSTRIDE], cells[tid]);

    // ================= grid barrier 2 =================
    __syncthreads();
    if (tid == 0) {
        __threadfence();
        atomicAdd(&ctr[2], 1u);
        while (atomicAdd(&ctr[2], 0u) < (unsigned)MB_) __builtin_amdgcn_s_sleep(1);
        __threadfence();
    }
    __syncthreads();

    // ================= phase 3: colfinal (per-block, atomic loads) =========
    // default candidate (0.0, anchor 0): every non-heavy entry of a valid gt
    // column is exactly 0.0 and anchor 0 is the smallest index.
    if (tid < 32) {
        unsigned long long mm =
            ((unsigned long long)enc_f32(0.0f) << 32) | 0xFFFFFFFFu;
        unsigned long long v = atomicMax(&pk[tid * PKSTRIDE], 0ull);  // pure load
        if (v > mm) mm = v;
        pk32[tid] = mm;
    }
    __syncthreads();

    // ================= phase 4: loss =================
    const int a = t & (A_ - 1);
    // atomic load: other blocks atomicMax'd this line in L2; plain load could
    // hit this CU's stale L1 copy from phase 1.
    unsigned long long rk2 = atomicMax(&rowMaxArg[t], 0ull);
    unsigned ehi = (unsigned)(rk2 >> 32);
    int arg = (G_ - 1) - (int)(rk2 & 0xFu);

    bool forcedf = false;
#pragma unroll
    for (int g = 0; g < G_; ++g) {
        unsigned long long pkv = pk32[b * G_ + g];
        float lab = ann[((size_t)b * G_ + g) * 6 + 5];
        unsigned hi = (unsigned)(pkv >> 32);
        unsigned ai = 0xFFFFFFFFu - (unsigned)pkv;
        forcedf |= (lab != -1.0f) && (hi < ENC_HALF) && (ai == (unsigned)a);
    }

    bool pos = (ehi >= ENC_HALF) || forcedf;
    const float* g6 = ann + ((size_t)b * G_ + arg) * 6;
    int cls = (int)g6[5];

    float csum = 0.f;
    if (pos || ehi < ENC_04) {
        const float* pr = cls_p + (size_t)t * C_;
#pragma unroll
        for (int c = 0; c < C_; ++c) {
            float tgt = (pos && c == cls) ? 1.f : 0.f;
            float pv = fminf(fmaxf(pr[c], 1e-4f), 1.f - 1e-4f);
            float af = (tgt == 1.f) ? 0.25f : 0.75f;
            float x = (tgt == 1.f) ? (1.f - pv) : pv;
            float fw = af * x * x;
            float bce = -(tgt * logf(pv + 1e-6f) + (1.f - tgt) * logf(1.f - pv + 1e-6f));
            csum += fw * bce;
        }
    }

    float rsum = 0.f;
    if (pos) {
        const float* ex = anc + (size_t)t * 5;
        const float* rp = reg_p + (size_t)t * 5;
        float ew = fmaxf(ex[2], 1.f), eh2 = fmaxf(ex[3], 1.f);
        float gw = fmaxf(g6[2], 1.f), gh = fmaxf(g6[3], 1.f);
        float tg[5];
        tg[0] = 10.f * (g6[0] - ex[0]) / ew;
        tg[1] = 10.f * (g6[1] - ex[1]) / eh2;
        tg[2] = 10.f * logf(gw / ew);
        tg[3] = 5.f * logf(gh / eh2);
        tg[4] = 15.f * (tanf(g6[4] * D2Rf) - tanf(ex[4] * D2Rf));
        const float BETAf = (float)(1.0 / 9.0);
#pragma unroll
        for (int i = 0; i < 5; ++i) {
            float d = fabsf(rp[i] - tg[i]);
            rsum += (d < BETAf) ? 0.5f * d * d / BETAf : d - 0.5f * BETAf;
        }
    }

    sc[tid] = csum; sr[tid] = rsum; sp[tid] = pos ? 1 : 0;
    __syncthreads();
    for (int s = MT_ / 2; s > 0; s >>= 1) {
        if (tid < s) {
            sc[tid] += sc[tid + s];
            sr[tid] += sr[tid + s];
            sp[tid] += sp[tid + s];
        }
        __syncthreads();
    }
    if (tid == 0) {
        pcls[blockIdx.x] = sc[0];
        preg[blockIdx.x] = sr[0];
        pnp[blockIdx.x] = sp[0];
        __threadfence();
        unsigned v = atomicAdd(&ctr[3], 1u);
        lastFlag = (v == (unsigned)(MB_ - 1));
    }
    __syncthreads();

    // ====== phase 5: last block only -- deterministic ordered combine ======
    if (lastFlag) {
        if (tid < MB_) {   // parallel atomic loads into LDS (bypass stale L1)
            sc[tid] = atomicAdd(&pcls[tid], 0.f);
            sr[tid] = atomicAdd(&preg[tid], 0.f);
            sp[tid] = atomicAdd(&pnp[tid], 0);
        }
        __syncthreads();
        if (tid == 0) {
            const int BPI = MB_ / B_;   // 64 blocks per image
            float cm = 0.f, rm = 0.f;
            for (int bb = 0; bb < B_; ++bb) {
                float cs = 0.f, rs = 0.f; int np = 0;
                for (int i = 0; i < BPI; ++i) {
                    cs += sc[bb * BPI + i];
                    rs += sr[bb * BPI + i];
                    np += sp[bb * BPI + i];
                }
                bool has = false;
                for (int g = 0; g < G_; ++g)
                    if (ann[((size_t)bb * G_ + g) * 6 + 5] != -1.0f) has = true;
                float c_ = cs / fmaxf((float)np, 1.f);
                int d5 = np * 5; if (d5 < 1) d5 = 1;
                float r_ = (np > 0) ? rs / (float)d5 : 0.f;
                cm += has ? c_ : 0.f;
                rm += has ? r_ : 0.f;
            }
            out[0] = cm / (float)B_;
            out[1] = rm / (float)B_;
        }
    }
}

// ---------------------------------------------------------------------------
extern "C" void kernel_launch(void* const* d_in, const int* in_sizes, int n_in,
                              void* d_out, int out_size, void* d_ws, size_t ws_size,
                              hipStream_t stream) {
    const float* cls_p = (const float*)d_in[0];   // (B,A,C)
    const float* reg_p = (const float*)d_in[1];   // (B,A,5)
    const float* anc   = (const float*)d_in[2];   // (B,A,5)
    const float* ann   = (const float*)d_in[3];   // (B,G,6)
    float* out = (float*)d_out;

    // workspace layout (init kernel zeroes ctr + pk each call)
    char* ws = (char*)d_ws;
    unsigned* ctrp = (unsigned*)ws;                                  // 4 u32
    unsigned long long* pk = (unsigned long long*)(ws + 256);        // 32*PKSTRIDE u64 (4 KB)
    unsigned long long* rowMaxArg =
        (unsigned long long*)(ws + 256 + 32 * PKSTRIDE * 8);         // 256 KB
    unsigned* wl = (unsigned*)(rowMaxArg + (size_t)B_ * A_);         // 2 MB max
    float* pcls = (float*)(wl + (size_t)B_ * A_ * G_);               // MB_
    float* preg = pcls + MB_;
    int*   pnp  = (int*)(preg + MB_);

    init_kernel<<<1, 256, 0, stream>>>(ctrp, pk);
    mega_kernel<<<MB_, MT_, 0, stream>>>(cls_p, reg_p, anc, ann, ctrp, pk, wl,
                                         rowMaxArg, pcls, preg, pnp, out);
}

// Round 8
// 65.249 us; speedup vs baseline: 1.0190x; 1.0190x over previous
//
#include <hip/hip_runtime.h>

#define B_ 2
#define A_ 16384
#define C_ 15
#define G_ 16
#define D2Rf 0.017453292519943295f
#define ENC_HALF 0xBF000000u   // enc(0.5f)
#define ENC_04   0xBECCCCCDu   // enc(0.4f)
#define MB_ 128                // mega blocks (<= 256 CUs -> co-resident)
#define MT_ 256                // threads per block; MB_*MT_ == B_*A_
#define SEGCAP 4096            // per-block worklist capacity (= 256*16 max)

__device__ __forceinline__ unsigned enc_f32(float f) {
    unsigned u = __float_as_uint(f);
    return u ^ ((u >> 31) ? 0xFFFFFFFFu : 0x80000000u);
}

// ---------------------------------------------------------------------------
// Rotated IoU, replicating the JAX reference op-for-op in fp32.
// (verified absmax 0.0 in R1-R7; all indexing compile-time static)
// ---------------------------------------------------------------------------
__device__ __forceinline__ void rect_corners5(const float* b, float X[4], float Y[4],
                                              float* cth, float* sth) {
    float th = b[4] * D2Rf;
    float c = cosf(th), s = sinf(th);
    *cth = c; *sth = s;
    const float SX[4] = {-1.f, 1.f, 1.f, -1.f};
    const float SY[4] = {-1.f, -1.f, 1.f, 1.f};
    float hw = 0.5f * b[2], hh = 0.5f * b[3];
#pragma unroll
    for (int i = 0; i < 4; ++i) {
        float dx = hw * SX[i];
        float dy = hh * SY[i];
        X[i] = b[0] + dx * c - dy * s;
        Y[i] = b[1] + dx * s + dy * c;
    }
}

__device__ __forceinline__ float rotated_iou_pair(const float* ab, const float* gb) {
    float ax[4], ay[4], gx[4], gy[4];
    float cA, sA, cG, sG;
    rect_corners5(ab, ax, ay, &cA, &sA);
    rect_corners5(gb, gx, gy, &cG, &sG);

    float rx[24], ry[24];
    unsigned msk = 0u;

#pragma unroll
    for (int i = 0; i < 4; ++i) {
        float dx = ax[i] - gb[0], dy = ay[i] - gb[1];
        float lx = dx * cG + dy * sG;
        float ly = -dx * sG + dy * cG;
        bool in = (fabsf(lx) <= 0.5f * gb[2] + 1e-4f) && (fabsf(ly) <= 0.5f * gb[3] + 1e-4f);
        rx[i] = ax[i]; ry[i] = ay[i];
        if (in) msk |= (1u << i);
    }
#pragma unroll
    for (int i = 0; i < 4; ++i) {
        float dx = gx[i] - ab[0], dy = gy[i] - ab[1];
        float lx = dx * cA + dy * sA;
        float ly = -dx * sA + dy * cA;
        bool in = (fabsf(lx) <= 0.5f * ab[2] + 1e-4f) && (fabsf(ly) <= 0.5f * ab[3] + 1e-4f);
        rx[4 + i] = gx[i]; ry[4 + i] = gy[i];
        if (in) msk |= (1u << (4 + i));
    }
#pragma unroll
    for (int i = 0; i < 4; ++i) {
        float p0x = ax[i], p0y = ay[i];
        float p1x = ax[(i + 1) & 3], p1y = ay[(i + 1) & 3];
        float d1x = p1x - p0x, d1y = p1y - p0y;
#pragma unroll
        for (int j = 0; j < 4; ++j) {
            float q0x = gx[j], q0y = gy[j];
            float q1x = gx[(j + 1) & 3], q1y = gy[(j + 1) & 3];
            float d2x = q1x - q0x, d2y = q1y - q0y;
            float rrx = q0x - p0x, rry = q0y - p0y;
            float den = d1x * d2y - d1y * d2x;
            float safe = (fabsf(den) < 1e-8f) ? 1.f : den;
            float t = (rrx * d2y - rry * d2x) / safe;
            float u = (rrx * d1y - rry * d1x) / safe;
            bool ok = (fabsf(den) >= 1e-8f) && (t >= 0.f) && (t <= 1.f) && (u >= 0.f) && (u <= 1.f);
            int k = 8 + i * 4 + j;
            rx[k] = p0x + t * d1x;
            ry[k] = p0y + t * d1y;
            if (ok) msk |= (1u << k);
        }
    }

    int cnt = __popc(msk);
    float sx = 0.f, sy = 0.f;
#pragma unroll
    for (int k = 0; k < 24; ++k)
        if ((msk >> k) & 1u) { sx += rx[k]; sy += ry[k]; }
    float cnf = fmaxf((float)cnt, 1.f);
    float cenx = sx / cnf, ceny = sy / cnf;

    float ang[24];
#pragma unroll
    for (int k = 0; k < 24; ++k) {
        if ((msk >> k) & 1u) {
            rx[k] -= cenx; ry[k] -= ceny;
            ang[k] = atan2f(ry[k], rx[k]);
        } else {
            rx[k] = 0.f; ry[k] = 0.f;
            ang[k] = 1e9f;
        }
    }

    int rnk[24];
#pragma unroll
    for (int k = 0; k < 24; ++k) {
        int r = 0;
#pragma unroll
        for (int j = 0; j < 24; ++j)
            r += (ang[j] < ang[k]) || (ang[j] == ang[k] && j < k);
        rnk[k] = r;
    }

    float ssum = 0.f;
#pragma unroll
    for (int k = 0; k < 24; ++k) {
        if ((msk >> k) & 1u) {
            int tgt = (rnk[k] + 1 == cnt) ? 0 : rnk[k] + 1;
            float qx = 0.f, qy = 0.f;
#pragma unroll
            for (int j = 0; j < 24; ++j) {
                if (((msk >> j) & 1u) && rnk[j] == tgt) { qx = rx[j]; qy = ry[j]; }
            }
            ssum += rx[k] * qy - ry[k] * qx;
        }
    }
    float inter = (cnt >= 3) ? 0.5f * fabsf(ssum) : 0.f;
    float uni = ab[2] * ab[3] + gb[2] * gb[3] - inter;
    return inter / fmaxf(uni, 1e-8f);
}

// ---------------------------------------------------------------------------
// grid barrier: arrivals are RMW (128 total); polling is a relaxed agent-scope
// atomic LOAD (read-through, non-serializing) + s_sleep backoff. R7's RMW
// polling congested the line (~25us/barrier). __threadfence() provides
// release (L2 writeback) / acquire (cache invalidate) around the barrier.
// ---------------------------------------------------------------------------
__device__ __forceinline__ void grid_barrier(unsigned* c) {
    __syncthreads();
    if (threadIdx.x == 0) {
        __threadfence();   // release our stores
        __hip_atomic_fetch_add(c, 1u, __ATOMIC_RELAXED, __HIP_MEMORY_SCOPE_AGENT);
        while (__hip_atomic_load(c, __ATOMIC_RELAXED, __HIP_MEMORY_SCOPE_AGENT)
               < (unsigned)MB_)
            __builtin_amdgcn_s_sleep(2);
        __threadfence();   // acquire others' stores
    }
    __syncthreads();
}

// ---------------------------------------------------------------------------
// init: zero barrier counters + heavy-rowkey array (exactly 1 u64/thread).
// ---------------------------------------------------------------------------
__global__ void init_kernel(unsigned* __restrict__ ctr,
                            unsigned long long* __restrict__ rowHeavy) {
    int t = blockIdx.x * MT_ + threadIdx.x;
    rowHeavy[t] = 0ull;
    if (blockIdx.x == 0 && threadIdx.x < 4) ctr[threadIdx.x] = 0u;
}

// ---------------------------------------------------------------------------
// mega: gate -> bar -> globally-balanced heavy -> bar -> colfinal+loss+final.
// 128 blocks x 256 threads (1 thread per anchor in gate/loss phases).
// Worklist = deterministic per-block segments; heavy derives global balance
// by scanning the 128 counts in LDS and binary-searching the item index.
// All cross-block combines are max over monotone packed keys or fixed-order
// sums -> bit-deterministic.
// ---------------------------------------------------------------------------
__global__ void __launch_bounds__(MT_, 1)
mega_kernel(const float* __restrict__ cls_p,
            const float* __restrict__ reg_p,
            const float* __restrict__ anc,
            const float* __restrict__ ann,
            unsigned* __restrict__ ctr,
            unsigned* __restrict__ seg,        // MB_*SEGCAP
            unsigned* __restrict__ segcnt,     // MB_
            unsigned long long* __restrict__ rowHeavy,   // B_*A_ (init: 0)
            unsigned long long* __restrict__ partials,   // MB_*32
            float* __restrict__ pcls,
            float* __restrict__ preg,
            int* __restrict__ pnp,
            float* __restrict__ out) {
    __shared__ int ss[MT_];
    __shared__ unsigned inc[MB_];              // inclusive item-count scan
    __shared__ unsigned long long cells[32];
    __shared__ unsigned long long red[MT_];
    __shared__ unsigned long long pk32[32];
    __shared__ float sc[MT_], sr[MT_];
    __shared__ int sp[MT_];
    __shared__ int lastFlag;

    const int tid = threadIdx.x;
    const int t = blockIdx.x * MT_ + tid;      // global anchor id
    const int b = t >> 14;

    if (tid < 32) cells[tid] = 0ull;

    // ================= phase 1: gate =================
    const float* ab = anc + (size_t)t * 5;
    float a0 = ab[0], a1 = ab[1], a2 = ab[2], a3 = ab[3];
    float sa = 0.5f * fmaxf(a2, a3);

    unsigned passmask = 0u;
    unsigned long long rkLight = 0ull;         // stays in a register to phase 4
#pragma unroll
    for (int g = 0; g < G_; ++g) {
        const float* gb = ann + ((size_t)b * G_ + g) * 6;  // uniform, cached
        float v;
        if (gb[5] == -1.0f) {
            v = -1.0f;
        } else {
            float sb = 0.5f * fmaxf(gb[2], gb[3]);
            float iw = fminf(a0 + sa, gb[0] + sb) - fmaxf(a0 - sa, gb[0] - sb);
            iw = fmaxf(iw, 0.f);
            float ih = fminf(a1 + sa, gb[1] + sb) - fmaxf(a1 - sa, gb[1] - sb);
            ih = fmaxf(ih, 0.f);
            float inter = iw * ih;
            float uni = 4.f * sa * sa + 4.f * sb * sb - inter;
            float ind = inter / fmaxf(uni, 1e-8f);
            if (ind > 0.1f) passmask |= (1u << g);
            v = 0.f;  // placeholder <= any heavy IoU, same tiebreak bits
        }
        unsigned long long key =
            ((unsigned long long)enc_f32(v) << 32) | (unsigned)(G_ - 1 - g);
        if (key > rkLight) rkLight = key;
    }

    // block scan -> deterministic per-block segment
    int cnt = __popc(passmask);
    ss[tid] = cnt;
    __syncthreads();
    for (int s = 1; s < MT_; s <<= 1) {
        int v = (tid >= s) ? ss[tid - s] : 0;
        __syncthreads();
        ss[tid] += v;
        __syncthreads();
    }
    unsigned p = (unsigned)(ss[tid] - cnt);
    unsigned* mySeg = seg + (size_t)blockIdx.x * SEGCAP;
#pragma unroll
    for (int g = 0; g < G_; ++g) {
        if ((passmask >> g) & 1u) mySeg[p++] = ((unsigned)tid << 4) | (unsigned)g;
    }
    if (tid == 0) segcnt[blockIdx.x] = (unsigned)ss[MT_ - 1];

    grid_barrier(&ctr[1]);

    // ========== phase 2: globally balanced heavy ==========
    // scan the 128 segment counts (plain loads, post-acquire) in LDS
    if (tid < MB_) inc[tid] = segcnt[tid];
    __syncthreads();
    for (int s = 1; s < MB_; s <<= 1) {
        unsigned v = (tid < MB_ && tid >= s) ? inc[tid - s] : 0u;
        __syncthreads();
        if (tid < MB_) inc[tid] += v;
        __syncthreads();
    }
    const unsigned n = inc[MB_ - 1];

    for (unsigned i = (unsigned)(blockIdx.x * MT_ + tid); i < n; i += MB_ * MT_) {
        // binary search: first s with inc[s] > i
        int lo = 0, hi = MB_ - 1;
        while (lo < hi) {
            int mid = (lo + hi) >> 1;
            if (inc[mid] > i) hi = mid; else lo = mid + 1;
        }
        unsigned base = (lo == 0) ? 0u : inc[lo - 1];
        unsigned e = seg[(size_t)lo * SEGCAP + (i - base)];
        int t2 = lo * MT_ + (int)(e >> 4);
        int g = (int)(e & 15u);
        int b2 = t2 >> 14;
        const float* ab2 = anc + (size_t)t2 * 5;
        const float* gb2 = ann + ((size_t)b2 * G_ + g) * 6;
        float v = rotated_iou_pair(ab2, gb2);
        unsigned long long ev = (unsigned long long)enc_f32(v);
        atomicMax(&rowHeavy[t2], (ev << 32) | (unsigned)(G_ - 1 - g));
        int aIdx = t2 & (A_ - 1);
        atomicMax(&cells[b2 * G_ + g], (ev << 32) | (0xFFFFFFFFu - (unsigned)aIdx));
    }
    __syncthreads();
    if (tid < 32) partials[(size_t)blockIdx.x * 32 + tid] = cells[tid];

    grid_barrier(&ctr[2]);

    // ===== phase 3: colfinal (redundant per-block reduce, plain loads) =====
    // default candidate (0.0, anchor 0): every non-heavy entry of a valid gt
    // column is exactly 0.0 and anchor 0 is the smallest index.
    {
        int cell = tid & 31, chunk = tid >> 5;   // 8 chunks x 16 blocks
        unsigned long long m = 0ull;
        for (int blk = chunk * (MB_ / 8); blk < (chunk + 1) * (MB_ / 8); ++blk) {
            unsigned long long v = partials[(size_t)blk * 32 + cell];
            if (v > m) m = v;
        }
        red[tid] = m;
    }
    __syncthreads();
    if (tid < 32) {
        unsigned long long mm =
            ((unsigned long long)enc_f32(0.0f) << 32) | 0xFFFFFFFFu;
        for (int c = 0; c < 8; ++c) {
            unsigned long long v = red[c * 32 + tid];
            if (v > mm) mm = v;
        }
        pk32[tid] = mm;
    }
    __syncthreads();

    // ================= phase 4: loss =================
    const int a = t & (A_ - 1);
    unsigned long long rk2 = rowHeavy[t];      // plain load, post-acquire
    if (rkLight > rk2) rk2 = rkLight;
    unsigned ehi = (unsigned)(rk2 >> 32);
    int arg = (G_ - 1) - (int)(rk2 & 0xFu);

    bool forcedf = false;
#pragma unroll
    for (int g = 0; g < G_; ++g) {
        unsigned long long pkv = pk32[b * G_ + g];
        float lab = ann[((size_t)b * G_ + g) * 6 + 5];
        unsigned hi = (unsigned)(pkv >> 32);
        unsigned ai = 0xFFFFFFFFu - (unsigned)pkv;
        forcedf |= (lab != -1.0f) && (hi < ENC_HALF) && (ai == (unsigned)a);
    }

    bool pos = (ehi >= ENC_HALF) || forcedf;
    const float* g6 = ann + ((size_t)b * G_ + arg) * 6;
    int cls = (int)g6[5];

    float csum = 0.f;
    if (pos || ehi < ENC_04) {
        const float* pr = cls_p + (size_t)t * C_;
#pragma unroll
        for (int c = 0; c < C_; ++c) {
            float tgt = (pos && c == cls) ? 1.f : 0.f;
            float pv = fminf(fmaxf(pr[c], 1e-4f), 1.f - 1e-4f);
            float af = (tgt == 1.f) ? 0.25f : 0.75f;
            float x = (tgt == 1.f) ? (1.f - pv) : pv;
            float fw = af * x * x;
            float bce = -(tgt * logf(pv + 1e-6f) + (1.f - tgt) * logf(1.f - pv + 1e-6f));
            csum += fw * bce;
        }
    }

    float rsum = 0.f;
    if (pos) {
        const float* ex = anc + (size_t)t * 5;
        const float* rp = reg_p + (size_t)t * 5;
        float ew = fmaxf(ex[2], 1.f), eh2 = fmaxf(ex[3], 1.f);
        float gw = fmaxf(g6[2], 1.f), gh = fmaxf(g6[3], 1.f);
        float tg[5];
        tg[0] = 10.f * (g6[0] - ex[0]) / ew;
        tg[1] = 10.f * (g6[1] - ex[1]) / eh2;
        tg[2] = 10.f * logf(gw / ew);
        tg[3] = 5.f * logf(gh / eh2);
        tg[4] = 15.f * (tanf(g6[4] * D2Rf) - tanf(ex[4] * D2Rf));
        const float BETAf = (float)(1.0 / 9.0);
#pragma unroll
        for (int i = 0; i < 5; ++i) {
            float d = fabsf(rp[i] - tg[i]);
            rsum += (d < BETAf) ? 0.5f * d * d / BETAf : d - 0.5f * BETAf;
        }
    }

    sc[tid] = csum; sr[tid] = rsum; sp[tid] = pos ? 1 : 0;
    __syncthreads();
    for (int s = MT_ / 2; s > 0; s >>= 1) {
        if (tid < s) {
            sc[tid] += sc[tid + s];
            sr[tid] += sr[tid + s];
            sp[tid] += sp[tid + s];
        }
        __syncthreads();
    }
    if (tid == 0) {
        pcls[blockIdx.x] = sc[0];
        preg[blockIdx.x] = sr[0];
        pnp[blockIdx.x] = sp[0];
        __threadfence();   // release partial sums
        unsigned v = __hip_atomic_fetch_add(&ctr[3], 1u, __ATOMIC_RELAXED,
                                            __HIP_MEMORY_SCOPE_AGENT);
        lastFlag = (v == (unsigned)(MB_ - 1));
    }
    __syncthreads();

    // ====== phase 5: last block only -- deterministic ordered combine ======
    if (lastFlag) {
        __threadfence();   // acquire all blocks' partial sums
        if (tid < MB_) {
            sc[tid] = pcls[tid];
            sr[tid] = preg[tid];
            sp[tid] = pnp[tid];
        }
        __syncthreads();
        if (tid == 0) {
            const int BPI = MB_ / B_;   // 64 blocks per image
            float cm = 0.f, rm = 0.f;
            for (int bb = 0; bb < B_; ++bb) {
                float cs = 0.f, rs = 0.f; int np = 0;
                for (int i = 0; i < BPI; ++i) {
                    cs += sc[bb * BPI + i];
                    rs += sr[bb * BPI + i];
                    np += sp[bb * BPI + i];
                }
                bool has = false;
                for (int g = 0; g < G_; ++g)
                    if (ann[((size_t)bb * G_ + g) * 6 + 5] != -1.0f) has = true;
                float c_ = cs / fmaxf((float)np, 1.f);
                int d5 = np * 5; if (d5 < 1) d5 = 1;
                float r_ = (np > 0) ? rs / (float)d5 : 0.f;
                cm += has ? c_ : 0.f;
                rm += has ? r_ : 0.f;
            }
            out[0] = cm / (float)B_;
            out[1] = rm / (float)B_;
        }
    }
}

// ---------------------------------------------------------------------------
extern "C" void kernel_launch(void* const* d_in, const int* in_sizes, int n_in,
                              void* d_out, int out_size, void* d_ws, size_t ws_size,
                              hipStream_t stream) {
    const float* cls_p = (const float*)d_in[0];   // (B,A,C)
    const float* reg_p = (const float*)d_in[1];   // (B,A,5)
    const float* anc   = (const float*)d_in[2];   // (B,A,5)
    const float* ann   = (const float*)d_in[3];   // (B,G,6)
    float* out = (float*)d_out;

    // workspace layout (init zeroes ctr + rowHeavy each call)
    char* ws = (char*)d_ws;
    unsigned* ctrp = (unsigned*)ws;                                   // 4 u32
    unsigned long long* rowHeavy = (unsigned long long*)(ws + 256);   // 256 KB
    unsigned long long* partials = rowHeavy + (size_t)B_ * A_;        // MB_*32*8 = 32 KB
    unsigned* segcnt = (unsigned*)(partials + (size_t)MB_ * 32);      // MB_ u32
    unsigned* seg    = segcnt + MB_;                                  // MB_*SEGCAP*4 = 2 MB
    float* pcls = (float*)(seg + (size_t)MB_ * SEGCAP);               // MB_
    float* preg = pcls + MB_;
    int*   pnp  = (int*)(preg + MB_);

    init_kernel<<<MB_, MT_, 0, stream>>>(ctrp, rowHeavy);
    mega_kernel<<<MB_, MT_, 0, stream>>>(cls_p, reg_p, anc, ann, ctrp,
                                         seg, segcnt, rowHeavy, partials,
                                         pcls, preg, pnp, out);
}

// Round 9
// 45.691 us; speedup vs baseline: 1.4552x; 1.4281x over previous
//
#include <hip/hip_runtime.h>

#define B_ 2
#define A_ 16384
#define C_ 15
#define G_ 16
#define D2Rf 0.017453292519943295f
#define ENC_HALF 0xBF000000u   // enc(0.5f)
#define ENC_04   0xBECCCCCDu   // enc(0.4f)
#define NSEG 128               // gate blocks / segments
#define HB_ 256                // heavy blocks (1 per CU)
#define LB_ 128                // loss blocks
#define SEGCAP 4096            // per-segment worklist capacity (256*16 max)

__device__ __forceinline__ unsigned enc_f32(float f) {
    unsigned u = __float_as_uint(f);
    return u ^ ((u >> 31) ? 0xFFFFFFFFu : 0x80000000u);
}

// ---------------------------------------------------------------------------
// Rotated IoU, replicating the JAX reference op-for-op in fp32.
// (verified absmax 0.0 in R1-R8; all indexing compile-time static)
// ---------------------------------------------------------------------------
__device__ __forceinline__ void rect_corners5(const float* b, float X[4], float Y[4],
                                              float* cth, float* sth) {
    float th = b[4] * D2Rf;
    float c = cosf(th), s = sinf(th);
    *cth = c; *sth = s;
    const float SX[4] = {-1.f, 1.f, 1.f, -1.f};
    const float SY[4] = {-1.f, -1.f, 1.f, 1.f};
    float hw = 0.5f * b[2], hh = 0.5f * b[3];
#pragma unroll
    for (int i = 0; i < 4; ++i) {
        float dx = hw * SX[i];
        float dy = hh * SY[i];
        X[i] = b[0] + dx * c - dy * s;
        Y[i] = b[1] + dx * s + dy * c;
    }
}

__device__ __forceinline__ float rotated_iou_pair(const float* ab, const float* gb) {
    float ax[4], ay[4], gx[4], gy[4];
    float cA, sA, cG, sG;
    rect_corners5(ab, ax, ay, &cA, &sA);
    rect_corners5(gb, gx, gy, &cG, &sG);

    float rx[24], ry[24];
    unsigned msk = 0u;

#pragma unroll
    for (int i = 0; i < 4; ++i) {
        float dx = ax[i] - gb[0], dy = ay[i] - gb[1];
        float lx = dx * cG + dy * sG;
        float ly = -dx * sG + dy * cG;
        bool in = (fabsf(lx) <= 0.5f * gb[2] + 1e-4f) && (fabsf(ly) <= 0.5f * gb[3] + 1e-4f);
        rx[i] = ax[i]; ry[i] = ay[i];
        if (in) msk |= (1u << i);
    }
#pragma unroll
    for (int i = 0; i < 4; ++i) {
        float dx = gx[i] - ab[0], dy = gy[i] - ab[1];
        float lx = dx * cA + dy * sA;
        float ly = -dx * sA + dy * cA;
        bool in = (fabsf(lx) <= 0.5f * ab[2] + 1e-4f) && (fabsf(ly) <= 0.5f * ab[3] + 1e-4f);
        rx[4 + i] = gx[i]; ry[4 + i] = gy[i];
        if (in) msk |= (1u << (4 + i));
    }
#pragma unroll
    for (int i = 0; i < 4; ++i) {
        float p0x = ax[i], p0y = ay[i];
        float p1x = ax[(i + 1) & 3], p1y = ay[(i + 1) & 3];
        float d1x = p1x - p0x, d1y = p1y - p0y;
#pragma unroll
        for (int j = 0; j < 4; ++j) {
            float q0x = gx[j], q0y = gy[j];
            float q1x = gx[(j + 1) & 3], q1y = gy[(j + 1) & 3];
            float d2x = q1x - q0x, d2y = q1y - q0y;
            float rrx = q0x - p0x, rry = q0y - p0y;
            float den = d1x * d2y - d1y * d2x;
            float safe = (fabsf(den) < 1e-8f) ? 1.f : den;
            float t = (rrx * d2y - rry * d2x) / safe;
            float u = (rrx * d1y - rry * d1x) / safe;
            bool ok = (fabsf(den) >= 1e-8f) && (t >= 0.f) && (t <= 1.f) && (u >= 0.f) && (u <= 1.f);
            int k = 8 + i * 4 + j;
            rx[k] = p0x + t * d1x;
            ry[k] = p0y + t * d1y;
            if (ok) msk |= (1u << k);
        }
    }

    int cnt = __popc(msk);
    float sx = 0.f, sy = 0.f;
#pragma unroll
    for (int k = 0; k < 24; ++k)
        if ((msk >> k) & 1u) { sx += rx[k]; sy += ry[k]; }
    float cnf = fmaxf((float)cnt, 1.f);
    float cenx = sx / cnf, ceny = sy / cnf;

    float ang[24];
#pragma unroll
    for (int k = 0; k < 24; ++k) {
        if ((msk >> k) & 1u) {
            rx[k] -= cenx; ry[k] -= ceny;
            ang[k] = atan2f(ry[k], rx[k]);
        } else {
            rx[k] = 0.f; ry[k] = 0.f;
            ang[k] = 1e9f;
        }
    }

    int rnk[24];
#pragma unroll
    for (int k = 0; k < 24; ++k) {
        int r = 0;
#pragma unroll
        for (int j = 0; j < 24; ++j)
            r += (ang[j] < ang[k]) || (ang[j] == ang[k] && j < k);
        rnk[k] = r;
    }

    float ssum = 0.f;
#pragma unroll
    for (int k = 0; k < 24; ++k) {
        if ((msk >> k) & 1u) {
            int tgt = (rnk[k] + 1 == cnt) ? 0 : rnk[k] + 1;
            float qx = 0.f, qy = 0.f;
#pragma unroll
            for (int j = 0; j < 24; ++j) {
                if (((msk >> j) & 1u) && rnk[j] == tgt) { qx = rx[j]; qy = ry[j]; }
            }
            ssum += rx[k] * qy - ry[k] * qx;
        }
    }
    float inter = (cnt >= 3) ? 0.5f * fabsf(ssum) : 0.f;
    float uni = ab[2] * ab[3] + gb[2] * gb[3] - inter;
    return inter / fmaxf(uni, 1e-8f);
}

// ---------------------------------------------------------------------------
// K1: gate. 128 blocks x 256 thr. Square-IoU gate -> per-block segment +
// count (deterministic, no global atomics). Light rowkey plain-stored to
// rowMaxArg (overwrites stale data -> no init kernel). Zeroes K3's counter.
// ---------------------------------------------------------------------------
__global__ void __launch_bounds__(256, 1)
gate_kernel(const float* __restrict__ anc,
            const float* __restrict__ ann,
            unsigned long long* __restrict__ rowMaxArg,
            unsigned* __restrict__ seg,
            unsigned* __restrict__ segcnt,
            unsigned* __restrict__ ctr) {
    __shared__ int ss[256];
    const int tid = threadIdx.x;
    const int t = blockIdx.x * 256 + tid;   // global anchor id
    const int b = blockIdx.x >> 6;          // 64 blocks per image

    if (blockIdx.x == 0 && tid == 0) ctr[0] = 0u;  // K3 arrival counter

    const float* ab = anc + (size_t)t * 5;
    float a0 = ab[0], a1 = ab[1], a2 = ab[2], a3 = ab[3];
    float sa = 0.5f * fmaxf(a2, a3);

    unsigned passmask = 0u;
    unsigned long long rk = 0ull;
#pragma unroll
    for (int g = 0; g < G_; ++g) {
        const float* gb = ann + ((size_t)b * G_ + g) * 6;  // uniform, cached
        float v;
        if (gb[5] == -1.0f) {
            v = -1.0f;
        } else {
            float sb = 0.5f * fmaxf(gb[2], gb[3]);
            float iw = fminf(a0 + sa, gb[0] + sb) - fmaxf(a0 - sa, gb[0] - sb);
            iw = fmaxf(iw, 0.f);
            float ih = fminf(a1 + sa, gb[1] + sb) - fmaxf(a1 - sa, gb[1] - sb);
            ih = fmaxf(ih, 0.f);
            float inter = iw * ih;
            float uni = 4.f * sa * sa + 4.f * sb * sb - inter;
            float ind = inter / fmaxf(uni, 1e-8f);
            if (ind > 0.1f) passmask |= (1u << g);
            v = 0.f;  // placeholder <= any heavy IoU, same tiebreak bits
        }
        unsigned long long key =
            ((unsigned long long)enc_f32(v) << 32) | (unsigned)(G_ - 1 - g);
        if (key > rk) rk = key;
    }
    rowMaxArg[t] = rk;   // plain store; K2 atomicMaxes heavy keys on top

    // block scan -> deterministic per-block segment
    int cnt = __popc(passmask);
    ss[tid] = cnt;
    __syncthreads();
    for (int s = 1; s < 256; s <<= 1) {
        int v = (tid >= s) ? ss[tid - s] : 0;
        __syncthreads();
        ss[tid] += v;
        __syncthreads();
    }
    unsigned p = (unsigned)(ss[tid] - cnt);
    unsigned* mySeg = seg + (size_t)blockIdx.x * SEGCAP;
#pragma unroll
    for (int g = 0; g < G_; ++g) {
        if ((passmask >> g) & 1u) mySeg[p++] = ((unsigned)tid << 4) | (unsigned)g;
    }
    if (tid == 0) segcnt[blockIdx.x] = (unsigned)ss[255];
}

// ---------------------------------------------------------------------------
// K2: heavy. 256 blocks x 256 thr (1 block/CU; launch_bounds lifts the
// default 64-VGPR cap so the clip's working set stays in registers).
// Every block scans the 128 segment counts in LDS; grid-stride over global
// item index + binary search -> perfect balance, <=1 clip per lane.
// Row keys: scattered global atomicMax over K1's light values. Col keys:
// LDS cells -> per-block partials. Max on monotone packed keys = assoc/comm
// -> bit-deterministic regardless of scheduling.
// ---------------------------------------------------------------------------
__global__ void __launch_bounds__(256, 1)
heavy_kernel(const float* __restrict__ anc,
             const float* __restrict__ ann,
             const unsigned* __restrict__ seg,
             const unsigned* __restrict__ segcnt,
             unsigned long long* __restrict__ rowMaxArg,
             unsigned long long* __restrict__ partials) {
    __shared__ unsigned inc[NSEG];
    __shared__ unsigned long long cells[32];
    const int tid = threadIdx.x;

    if (tid < 32) cells[tid] = 0ull;
    if (tid < NSEG) inc[tid] = segcnt[tid];
    __syncthreads();
    for (int s = 1; s < NSEG; s <<= 1) {
        unsigned v = (tid < NSEG && tid >= s) ? inc[tid - s] : 0u;
        __syncthreads();
        if (tid < NSEG) inc[tid] += v;
        __syncthreads();
    }
    const unsigned n = inc[NSEG - 1];

    for (unsigned i = (unsigned)(blockIdx.x * 256 + tid); i < n; i += HB_ * 256) {
        // first segment s with inc[s] > i
        int lo = 0, hi = NSEG - 1;
        while (lo < hi) {
            int mid = (lo + hi) >> 1;
            if (inc[mid] > i) hi = mid; else lo = mid + 1;
        }
        unsigned base = (lo == 0) ? 0u : inc[lo - 1];
        unsigned e = seg[(size_t)lo * SEGCAP + (i - base)];
        int t2 = lo * 256 + (int)(e >> 4);
        int g = (int)(e & 15u);
        int b2 = t2 >> 14;
        const float* ab2 = anc + (size_t)t2 * 5;
        const float* gb2 = ann + ((size_t)b2 * G_ + g) * 6;
        float v = rotated_iou_pair(ab2, gb2);
        unsigned long long ev = (unsigned long long)enc_f32(v);
        atomicMax(&rowMaxArg[t2], (ev << 32) | (unsigned)(G_ - 1 - g));
        int aIdx = t2 & (A_ - 1);
        atomicMax(&cells[b2 * G_ + g], (ev << 32) | (0xFFFFFFFFu - (unsigned)aIdx));
    }
    __syncthreads();
    if (tid < 32) partials[(size_t)blockIdx.x * 32 + tid] = cells[tid];
}

// ---------------------------------------------------------------------------
// K3: colfinal + loss + final. 128 blocks x 256 thr.
// Each block redundantly reduces the HB_*32 col partials (L2-resident),
// computes per-anchor loss, writes block partials, and the last-arriving
// block does the deterministic ordered final combine (no spinning).
// ---------------------------------------------------------------------------
__global__ void __launch_bounds__(256, 1)
loss_kernel(const float* __restrict__ cls_p,
            const float* __restrict__ reg_p,
            const float* __restrict__ anc,
            const float* __restrict__ ann,
            const unsigned long long* __restrict__ rowMaxArg,
            const unsigned long long* __restrict__ partials,
            float* __restrict__ pcls,
            float* __restrict__ preg,
            int* __restrict__ pnp,
            unsigned* __restrict__ ctr,
            float* __restrict__ out) {
    __shared__ unsigned long long red[256];
    __shared__ unsigned long long pk32[32];
    __shared__ float sc[256], sr[256];
    __shared__ int sp[256];
    __shared__ int lastFlag;

    const int tid = threadIdx.x;

    // ---- colfinal: reduce HB_ x 32 partials; default candidate (0.0, a=0):
    // every non-heavy entry of a valid gt column is exactly 0.0 and anchor 0
    // is the smallest index, so colmax = max(best heavy, (0.0, anchor 0)).
    {
        int cell = tid & 31, chunk = tid >> 5;   // 8 chunks x 32 heavy-blocks
        unsigned long long m = 0ull;
        for (int blk = chunk * (HB_ / 8); blk < (chunk + 1) * (HB_ / 8); ++blk) {
            unsigned long long v = partials[(size_t)blk * 32 + cell];
            if (v > m) m = v;
        }
        red[tid] = m;
    }
    __syncthreads();
    if (tid < 32) {
        unsigned long long mm =
            ((unsigned long long)enc_f32(0.0f) << 32) | 0xFFFFFFFFu;
        for (int c = 0; c < 8; ++c) {
            unsigned long long v = red[c * 32 + tid];
            if (v > mm) mm = v;
        }
        pk32[tid] = mm;
    }
    __syncthreads();

    // ---- per-anchor loss ----
    const int t = blockIdx.x * 256 + tid;
    const int b = t >> 14;
    const int a = t & (A_ - 1);

    unsigned long long rk = rowMaxArg[t];
    unsigned ehi = (unsigned)(rk >> 32);
    int arg = (G_ - 1) - (int)(rk & 0xFu);

    bool forcedf = false;
#pragma unroll
    for (int g = 0; g < G_; ++g) {
        unsigned long long pkv = pk32[b * G_ + g];
        float lab = ann[((size_t)b * G_ + g) * 6 + 5];
        unsigned hi = (unsigned)(pkv >> 32);
        unsigned ai = 0xFFFFFFFFu - (unsigned)pkv;
        forcedf |= (lab != -1.0f) && (hi < ENC_HALF) && (ai == (unsigned)a);
    }

    bool pos = (ehi >= ENC_HALF) || forcedf;
    const float* g6 = ann + ((size_t)b * G_ + arg) * 6;
    int cls = (int)g6[5];

    float csum = 0.f;
    if (pos || ehi < ENC_04) {
        const float* pr = cls_p + (size_t)t * C_;
#pragma unroll
        for (int c = 0; c < C_; ++c) {
            float tgt = (pos && c == cls) ? 1.f : 0.f;
            float pv = fminf(fmaxf(pr[c], 1e-4f), 1.f - 1e-4f);
            float af = (tgt == 1.f) ? 0.25f : 0.75f;
            float x = (tgt == 1.f) ? (1.f - pv) : pv;
            float fw = af * x * x;
            float bce = -(tgt * logf(pv + 1e-6f) + (1.f - tgt) * logf(1.f - pv + 1e-6f));
            csum += fw * bce;
        }
    }

    float rsum = 0.f;
    if (pos) {
        const float* ex = anc + (size_t)t * 5;
        const float* rp = reg_p + (size_t)t * 5;
        float ew = fmaxf(ex[2], 1.f), eh2 = fmaxf(ex[3], 1.f);
        float gw = fmaxf(g6[2], 1.f), gh = fmaxf(g6[3], 1.f);
        float tg[5];
        tg[0] = 10.f * (g6[0] - ex[0]) / ew;
        tg[1] = 10.f * (g6[1] - ex[1]) / eh2;
        tg[2] = 10.f * logf(gw / ew);
        tg[3] = 5.f * logf(gh / eh2);
        tg[4] = 15.f * (tanf(g6[4] * D2Rf) - tanf(ex[4] * D2Rf));
        const float BETAf = (float)(1.0 / 9.0);
#pragma unroll
        for (int i = 0; i < 5; ++i) {
            float d = fabsf(rp[i] - tg[i]);
            rsum += (d < BETAf) ? 0.5f * d * d / BETAf : d - 0.5f * BETAf;
        }
    }

    sc[tid] = csum; sr[tid] = rsum; sp[tid] = pos ? 1 : 0;
    __syncthreads();
    for (int s = 128; s > 0; s >>= 1) {
        if (tid < s) {
            sc[tid] += sc[tid + s];
            sr[tid] += sr[tid + s];
            sp[tid] += sp[tid + s];
        }
        __syncthreads();
    }
    if (tid == 0) {
        pcls[blockIdx.x] = sc[0];
        preg[blockIdx.x] = sr[0];
        pnp[blockIdx.x] = sp[0];
        __threadfence();   // release partials (writeback to coherent point)
        unsigned v = atomicAdd(ctr, 1u);   // single RMW, no spinning
        lastFlag = (v == (unsigned)(LB_ - 1));
    }
    __syncthreads();

    // ---- last-arriving block: deterministic ordered final combine ----
    if (lastFlag) {
        __threadfence();   // acquire (invalidate local caches)
        if (tid < LB_) {
            sc[tid] = pcls[tid];
            sr[tid] = preg[tid];
            sp[tid] = pnp[tid];
        }
        __syncthreads();
        if (tid == 0) {
            const int BPI = LB_ / B_;   // 64 blocks per image
            float cm = 0.f, rm = 0.f;
            for (int bb = 0; bb < B_; ++bb) {
                float cs = 0.f, rs = 0.f; int np = 0;
                for (int i = 0; i < BPI; ++i) {
                    cs += sc[bb * BPI + i];
                    rs += sr[bb * BPI + i];
                    np += sp[bb * BPI + i];
                }
                bool has = false;
                for (int g = 0; g < G_; ++g)
                    if (ann[((size_t)bb * G_ + g) * 6 + 5] != -1.0f) has = true;
                float c_ = cs / fmaxf((float)np, 1.f);
                int d5 = np * 5; if (d5 < 1) d5 = 1;
                float r_ = (np > 0) ? rs / (float)d5 : 0.f;
                cm += has ? c_ : 0.f;
                rm += has ? r_ : 0.f;
            }
            out[0] = cm / (float)B_;
            out[1] = rm / (float)B_;
        }
    }
}

// ---------------------------------------------------------------------------
extern "C" void kernel_launch(void* const* d_in, const int* in_sizes, int n_in,
                              void* d_out, int out_size, void* d_ws, size_t ws_size,
                              hipStream_t stream) {
    const float* cls_p = (const float*)d_in[0];   // (B,A,C)
    const float* reg_p = (const float*)d_in[1];   // (B,A,5)
    const float* anc   = (const float*)d_in[2];   // (B,A,5)
    const float* ann   = (const float*)d_in[3];   // (B,G,6)
    float* out = (float*)d_out;

    // workspace (every word consumed is rewritten each call; no memset)
    char* ws = (char*)d_ws;
    unsigned* ctrp = (unsigned*)ws;                                   // 256 B
    unsigned long long* rowMaxArg = (unsigned long long*)(ws + 256);  // 256 KB
    unsigned long long* partials = rowMaxArg + (size_t)B_ * A_;       // HB_*32*8 = 64 KB
    unsigned* segcnt = (unsigned*)(partials + (size_t)HB_ * 32);      // NSEG u32
    unsigned* seg    = segcnt + NSEG;                                 // NSEG*SEGCAP*4 = 2 MB
    float* pcls = (float*)(seg + (size_t)NSEG * SEGCAP);              // LB_
    float* preg = pcls + LB_;
    int*   pnp  = (int*)(preg + LB_);

    gate_kernel<<<NSEG, 256, 0, stream>>>(anc, ann, rowMaxArg, seg, segcnt, ctrp);
    heavy_kernel<<<HB_, 256, 0, stream>>>(anc, ann, seg, segcnt, rowMaxArg, partials);
    loss_kernel<<<LB_, 256, 0, stream>>>(cls_p, reg_p, anc, ann, rowMaxArg,
                                         partials, pcls, preg, pnp, ctrp, out);
}